// Round 9
// baseline (570.555 us; speedup 1.0000x reference)
//
#include <hip/hip_runtime.h>
#include <stdint.h>

typedef unsigned short u16;
typedef unsigned int u32;
typedef _Float16 f16;
typedef float v4f __attribute__((ext_vector_type(4)));
typedef f16 v8h __attribute__((ext_vector_type(8)));

#define CC 256
#define NNN 4096

__device__ __forceinline__ u16 f2h(float f) {
  union { f16 h; u16 u; } c; c.h = (f16)f; return c.u;
}
// monotone float<->uint encoding for atomicMax on fp32
__device__ __forceinline__ u32 encf(float f) {
  u32 u = __float_as_uint(f);
  return (u >> 31) ? ~u : (u | 0x80000000u);
}
__device__ __forceinline__ float decf(u32 u) {
  return (u >> 31) ? __uint_as_float(u & 0x7fffffffu) : __uint_as_float(~u);
}
__device__ __forceinline__ void async16(const void* g, void* l) {
  __builtin_amdgcn_global_load_lds(
      (const __attribute__((address_space(1))) uint32_t*)g,
      (__attribute__((address_space(3))) uint32_t*)l, 16, 0, 0);
}

// ---- W [256][256] fp32 -> Ws [256][256] single fp16, K(c)-fast ----
// (Wlo dropped: a~'s error is dominated by fp16(a) and fp16(a~) rounding;
//  W-rounding adds an ~equal independent term. R8 absmax 0.039 -> ~0.045.)
__global__ __launch_bounds__(256) void wsplit(const float* __restrict__ W,
                                              u16* __restrict__ Ws) {
  const int d = blockIdx.x, c = threadIdx.x;
  Ws[d * 256 + c] = f2h(W[d * 256 + c]);
}

// ---- per batch: in [C][N] fp32 -> T [N][256] fp16 (transposed, K-fast),
//      and Cb [C][N] fp16 (straight copy) ----
__global__ __launch_bounds__(256) void tsplit(const float* __restrict__ in,
                                              u16* __restrict__ T,
                                              u16* __restrict__ Cb) {
  __shared__ u16 th[64][65];
  const int bb = blockIdx.z;
  const int n0 = blockIdx.x * 64;
  const int c0 = blockIdx.y * 64;
  const int tx = threadIdx.x & 63;
  const int ty = threadIdx.x >> 6;  // 0..3
  const float* ib = in + (size_t)bb * CC * NNN;
  u16* Tb = T + (size_t)bb * NNN * 256;
  u16* Cbb = Cb + (size_t)bb * CC * NNN;
#pragma unroll
  for (int k = 0; k < 16; k++) {
    int r = ty + k * 4;
    float v = ib[(size_t)(c0 + r) * NNN + n0 + tx];
    u16 h = f2h(v);
    th[r][tx] = h;
    Cbb[(size_t)(c0 + r) * NNN + n0 + tx] = h;
  }
  __syncthreads();
#pragma unroll
  for (int k = 0; k < 16; k++) {
    int r = ty + k * 4;
    Tb[(size_t)(n0 + r) * 256 + c0 + tx] = th[tx][r];
  }
}

// ---- TN GEMM over fp16, per-operand k-masking (legacy; both sides now
// run unmasked K=256). BK=64, XOR-swizzled LDS.
// MODE 0: out = a~ single fp16, pitch 256.
// MODE 1: out = S fp32 + row/col max atomics; tiles XCD-clustered.
template <int MODE>
__global__ __launch_bounds__(256) void gemm_tn(
    const u16* __restrict__ A, long sAb, int pa, int ma,
    const u16* __restrict__ Bm, long sBb, int pb, int mb, int ktot,
    u16* __restrict__ outb, long sOb, float* __restrict__ S,
    u32* __restrict__ Mru, u32* __restrict__ Mcu) {
  const int bz = blockIdx.z;
  const u16* Ab = A + (size_t)bz * sAb;
  const u16* Bb = Bm + (size_t)bz * sBb;
  int m0, n0;
  if (MODE == 0) {
    m0 = blockIdx.x * 128;
    n0 = blockIdx.y * 128;
  } else {
    const int bidl = blockIdx.x + (int)gridDim.x * blockIdx.y;  // 0..1023
    const int xcd = bidl & 7, idx = bidl >> 3;
    const int mt = (xcd & 3) * 8 + (idx & 7);
    const int nt = (xcd >> 2) * 16 + (idx >> 3);
    m0 = mt * 128;
    n0 = nt * 128;
  }
  const int tid = threadIdx.x;
  const int wave = tid >> 6;
  const int lane = tid & 63;
  const int q = lane >> 4;
  const int l = lane & 15;
  const int l7 = l & 7;
  const int wm = (wave >> 1) * 64;
  const int wn = (wave & 1) * 64;
  const int sr = lane >> 3;  // row-in-group 0..7
  const int sp = lane & 7;   // LDS chunk position 0..7
  const int sg = sp ^ sr;    // global chunk index (swizzle)

  __shared__ alignas(16) u16 sA[128 * 64];
  __shared__ alignas(16) u16 sB[128 * 64];

  v4f zero = {0.f, 0.f, 0.f, 0.f};
  v4f acc[4][4];
#pragma unroll
  for (int i = 0; i < 4; i++)
#pragma unroll
    for (int j = 0; j < 4; j++) acc[i][j] = zero;

  for (int k0 = 0; k0 < ktot; k0 += 64) {
    const int kA = k0 & ma;
    const int kB = k0 & mb;
    __syncthreads();
#pragma unroll
    for (int ii = 0; ii < 4; ii++) {
      int r = wave * 32 + ii * 8 + sr;
      async16(Ab + (size_t)(m0 + r) * pa + kA + sg * 8,
              &sA[r * 64 + sp * 8]);
    }
#pragma unroll
    for (int ii = 0; ii < 4; ii++) {
      int r = wave * 32 + ii * 8 + sr;
      async16(Bb + (size_t)(n0 + r) * pb + kB + sg * 8,
              &sB[r * 64 + sp * 8]);
    }
    __syncthreads();
#pragma unroll
    for (int s = 0; s < 2; s++) {
      const int pa8 = (s * 4 + q) ^ l7;
      v8h af[4], bfr[4];
#pragma unroll
      for (int i = 0; i < 4; i++)
        af[i] = *(const v8h*)&sA[(wm + i * 16 + l) * 64 + pa8 * 8];
#pragma unroll
      for (int j = 0; j < 4; j++)
        bfr[j] = *(const v8h*)&sB[(wn + j * 16 + l) * 64 + pa8 * 8];
#pragma unroll
      for (int i = 0; i < 4; i++)
#pragma unroll
        for (int j = 0; j < 4; j++)
          acc[i][j] = __builtin_amdgcn_mfma_f32_16x16x32_f16(af[i], bfr[j],
                                                             acc[i][j], 0, 0, 0);
    }
  }

  if (MODE == 0) {
    u16* ob = outb + (size_t)bz * sOb;
#pragma unroll
    for (int i = 0; i < 4; i++)
#pragma unroll
      for (int j = 0; j < 4; j++)
#pragma unroll
        for (int r = 0; r < 4; r++) {
          int row = m0 + wm + i * 16 + q * 4 + r;
          int col = n0 + wn + j * 16 + l;
          ob[(size_t)row * 256 + col] = f2h(acc[i][j][r]);
        }
  } else {
#pragma unroll
    for (int i = 0; i < 4; i++)
#pragma unroll
      for (int j = 0; j < 4; j++)
#pragma unroll
        for (int r = 0; r < 4; r++) {
          int row = m0 + wm + i * 16 + q * 4 + r;  // S row n
          int col = n0 + wn + j * 16 + l;          // S col m
          S[(size_t)row * NNN + col] = acc[i][j][r];
        }
    // --- row max (over this block's 128 cols) ---
    float rm[4][4];
#pragma unroll
    for (int i = 0; i < 4; i++)
#pragma unroll
      for (int r = 0; r < 4; r++)
        rm[i][r] = fmaxf(fmaxf(acc[i][0][r], acc[i][1][r]),
                         fmaxf(acc[i][2][r], acc[i][3][r]));
#pragma unroll
    for (int off = 1; off < 16; off <<= 1)
#pragma unroll
      for (int i = 0; i < 4; i++)
#pragma unroll
        for (int r = 0; r < 4; r++)
          rm[i][r] = fmaxf(rm[i][r], __shfl_xor(rm[i][r], off));
    if (l == 0) {
#pragma unroll
      for (int i = 0; i < 4; i++)
#pragma unroll
        for (int r = 0; r < 4; r++)
          atomicMax(&Mru[m0 + wm + i * 16 + q * 4 + r], encf(rm[i][r]));
    }
    // --- col max (over this block's 128 rows) ---
    float cm[4];
#pragma unroll
    for (int j = 0; j < 4; j++) {
      float v = -3e38f;
#pragma unroll
      for (int i = 0; i < 4; i++)
#pragma unroll
        for (int r = 0; r < 4; r++) v = fmaxf(v, acc[i][j][r]);
      cm[j] = v;
    }
#pragma unroll
    for (int off = 16; off < 64; off <<= 1)
#pragma unroll
      for (int j = 0; j < 4; j++) cm[j] = fmaxf(cm[j], __shfl_xor(cm[j], off));
    if (q == 0) {
#pragma unroll
      for (int j = 0; j < 4; j++)
        atomicMax(&Mcu[n0 + wn + j * 16 + l], encf(cm[j]));
    }
  }
}

// ---- K-split PV partial with fused L accumulation. fp16 V/P, BK=64,
// swizzled LDS, XCD-clustered. R8 structure with ONE isolated change:
// S loads for step t+1 are issued into registers (sv[16]) BEFORE the
// drain barrier of step t, so S latency overlaps the async16-V drain.
// No indexing / LDS / grid changes; S is read-only (no hazard).
__global__ __launch_bounds__(256) void pv_part(
    const u16* __restrict__ aV, const u16* __restrict__ bV,
    const float* __restrict__ S, const u32* __restrict__ Mru,
    const u32* __restrict__ Mcu, float* __restrict__ part,
    float* __restrict__ Lp, int batch) {
  const int lin = blockIdx.x + 64 * (blockIdx.y + 2 * blockIdx.z);  // 0..511
  const int xcd = lin & 7;
  const int which = xcd & 1;
  const int split = xcd >> 1;
  const int x0 = (lin >> 3) * 64;
  const u16* Av = (which ? bV : aV) + (size_t)batch * (CC * NNN);
  const u32* Mst = which ? Mru : Mcu;
  float* Out = part + ((size_t)split * 2 + which) * (CC * NNN);
  float* Lpo = Lp + ((size_t)split * 2 + which) * NNN;

  const int tid = threadIdx.x;
  const int wave = tid >> 6, lane = tid & 63, q = lane >> 4, l = lane & 15;
  const int l7 = l & 7;
  const int sr = lane >> 3, sp = lane & 7, sg = sp ^ sr;
  // which=1 S-read coords: 64 x-rows x 4 chunks of 16 k
  const int xl = tid >> 2, ch = tid & 3;
  // which=0 S-read coords: 64 x-cols x 4 groups of 16 k-rows
  const int xs = tid & 63, kq = (tid >> 6) * 16;
  const int xr = which ? xl : xs;
  const int g0 = which ? ch * 2 : (tid >> 6) * 2;

  __shared__ alignas(16) u16 sA[256 * 64];
  __shared__ alignas(16) u16 sB[64 * 64];
  __shared__ float lsh[256];

  v4f zero = {0.f, 0.f, 0.f, 0.f};
  v4f acc[4][4];
#pragma unroll
  for (int i = 0; i < 4; i++)
#pragma unroll
    for (int j = 0; j < 4; j++) acc[i][j] = zero;

  const float mx = decf(Mst[x0 + xr]);
  float lsum = 0.f;
  const int kbeg = split * 1024;

  float sv[16];
  auto loadS = [&](int k0) {
    if (which) {
      const float* gp = S + (size_t)(x0 + xl) * NNN + k0 + ch * 16;
#pragma unroll
      for (int t4 = 0; t4 < 4; t4++) {
        float4 v = ((const float4*)gp)[t4];
        sv[t4 * 4 + 0] = v.x;
        sv[t4 * 4 + 1] = v.y;
        sv[t4 * 4 + 2] = v.z;
        sv[t4 * 4 + 3] = v.w;
      }
    } else {
      const float* gp = S + (size_t)(k0 + kq) * NNN + x0 + xs;
#pragma unroll
      for (int t = 0; t < 16; t++) sv[t] = gp[(size_t)t * NNN];
    }
  };
  auto packP = [&]() {
    float e[16];
#pragma unroll
    for (int t = 0; t < 16; t++) e[t] = __expf(sv[t] - mx);
#pragma unroll
    for (int t = 0; t < 16; t++) lsum += e[t];
    v8h pk0, pk1;
#pragma unroll
    for (int t = 0; t < 8; t++) {
      pk0[t] = (f16)e[t];
      pk1[t] = (f16)e[t + 8];
    }
    *(v8h*)&sB[xr * 64 + (g0 ^ (xr & 7)) * 8] = pk0;
    *(v8h*)&sB[xr * 64 + ((g0 + 1) ^ (xr & 7)) * 8] = pk1;
  };

  loadS(kbeg);  // prefetch step 0
  for (int t = 0; t < 16; t++) {
    const int k0 = kbeg + t * 64;
    __syncthreads();
#pragma unroll
    for (int ii = 0; ii < 8; ii++) {
      int r = wave * 64 + ii * 8 + sr;
      async16(Av + (size_t)r * NNN + k0 + sg * 8, &sA[r * 64 + sp * 8]);
    }
    packP();                      // exp + lsum + sB writes for step t
    if (t < 15) loadS(k0 + 64);   // issue next S loads before the drain
    __syncthreads();
#pragma unroll
    for (int s = 0; s < 2; s++) {
      const int pa8 = (s * 4 + q) ^ l7;
      v8h af[4], bfr[4];
#pragma unroll
      for (int i = 0; i < 4; i++)
        af[i] = *(const v8h*)&sA[(wave * 64 + i * 16 + l) * 64 + pa8 * 8];
#pragma unroll
      for (int j = 0; j < 4; j++)
        bfr[j] = *(const v8h*)&sB[(j * 16 + l) * 64 + pa8 * 8];
#pragma unroll
      for (int i = 0; i < 4; i++)
#pragma unroll
        for (int j = 0; j < 4; j++)
          acc[i][j] = __builtin_amdgcn_mfma_f32_16x16x32_f16(af[i], bfr[j],
                                                             acc[i][j], 0, 0, 0);
    }
  }

  // L partial reduction: 4 threads contribute per x
  __syncthreads();
  lsh[tid] = lsum;
  __syncthreads();
  if (tid < 64) {
    float t;
    if (which)
      t = (lsh[tid * 4] + lsh[tid * 4 + 1]) + (lsh[tid * 4 + 2] + lsh[tid * 4 + 3]);
    else
      t = (lsh[tid] + lsh[tid + 64]) + (lsh[tid + 128] + lsh[tid + 192]);
    Lpo[x0 + tid] = t;
  }

#pragma unroll
  for (int i = 0; i < 4; i++)
#pragma unroll
    for (int j = 0; j < 4; j++)
#pragma unroll
      for (int r = 0; r < 4; r++) {
        int c = wave * 64 + i * 16 + q * 4 + r;
        int x = x0 + j * 16 + l;
        Out[(size_t)c * NNN + x] = acc[i][j][r];
      }
}

// ---- reduce 4 K-split partials + L partials, apply 1/L, write output ----
__global__ __launch_bounds__(256) void pv_reduce(
    const float* __restrict__ part, const float* __restrict__ Lp,
    float* __restrict__ outA, float* __restrict__ outB, int batch) {
  const int bi = blockIdx.x;  // 0..511
  const int which = bi >> 8;
  const int c = bi & 255;
  float* Out = (which ? outB : outA) + (size_t)batch * CC * NNN +
               (size_t)c * NNN;
  const float* p0 = part + (size_t)which * (CC * NNN) + (size_t)c * NNN;
  const float* l0 = Lp + (size_t)which * NNN;
  const size_t ps = 2 * (size_t)CC * NNN;
  const size_t ls = 2 * (size_t)NNN;
  const int t = threadIdx.x;
#pragma unroll
  for (int xi = 0; xi < 4; xi++) {
    int x = xi * 1024 + t * 4;
    float4 a0 = *(const float4*)(p0 + x);
    float4 a1 = *(const float4*)(p0 + ps + x);
    float4 a2 = *(const float4*)(p0 + 2 * ps + x);
    float4 a3 = *(const float4*)(p0 + 3 * ps + x);
    float4 q0 = *(const float4*)(l0 + x);
    float4 q1 = *(const float4*)(l0 + ls + x);
    float4 q2 = *(const float4*)(l0 + 2 * ls + x);
    float4 q3 = *(const float4*)(l0 + 3 * ls + x);
    float4 o;
    o.x = ((a0.x + a1.x) + (a2.x + a3.x)) / ((q0.x + q1.x) + (q2.x + q3.x));
    o.y = ((a0.y + a1.y) + (a2.y + a3.y)) / ((q0.y + q1.y) + (q2.y + q3.y));
    o.z = ((a0.z + a1.z) + (a2.z + a3.z)) / ((q0.z + q1.z) + (q2.z + q3.z));
    o.w = ((a0.w + a1.w) + (a2.w + a3.w)) / ((q0.w + q1.w) + (q2.w + q3.w));
    *(float4*)(Out + x) = o;
  }
}

extern "C" void kernel_launch(void* const* d_in, const int* in_sizes, int n_in,
                              void* d_out, int out_size, void* d_ws,
                              size_t ws_size, hipStream_t stream) {
  const float* a = (const float*)d_in[0];
  const float* b = (const float*)d_in[1];
  const float* W = (const float*)d_in[2];
  float* out = (float*)d_out;

  char* ws = (char*)d_ws;
  u16* Ws = (u16*)(ws);                     // 131072 (256KB rsvd)
  u16* aT = (u16*)(ws + 262144);            // 4*4096*256*2 = 8388608
  u16* bT = (u16*)(ws + 8650752);           // 8388608
  u16* aCb = (u16*)(ws + 17039360);         // 8388608
  u16* bCb = (u16*)(ws + 25427968);         // 8388608
  u16* ats = (u16*)(ws + 33816576);         // 4*4096*256*2 = 8388608 (16MB rsvd)
  u32* Mru = (u32*)(ws + 50593792);         // [4][4096] u32 = 65536
  u32* Mcu = (u32*)(ws + 50659328);         // 65536
  float* Lp = (float*)(ws + 50724864);      // 131072
  float* Sbuf = (float*)(ws + 50855936);    // 67108864
  float* Ppart = (float*)(ws + 117964800);  // 33554432 -> ends ~151.5 MB

  wsplit<<<dim3(256), 256, 0, stream>>>(W, Ws);
  tsplit<<<dim3(64, 4, 4), 256, 0, stream>>>(a, aT, aCb);
  tsplit<<<dim3(64, 4, 4), 256, 0, stream>>>(b, bT, bCb);
  // a~[n][d] = sum_c aT[n][c] * W[d][c], K=256 single fp16 both sides,
  // output single fp16, pitch 256
  gemm_tn<0><<<dim3(32, 2, 4), 256, 0, stream>>>(
      aT, (long)NNN * 256, 256, 255, Ws, 0, 256, 255, 256,
      ats, (long)NNN * 256, nullptr, nullptr, nullptr);
  hipMemsetAsync(Mru, 0, 131072, stream);  // all 4 batches' Mru+Mcu

  for (int p = 0; p < 4; p++) {
    const u16* atp = ats + (size_t)p * NNN * 256;
    const u16* btp = bT + (size_t)p * NNN * 256;
    // S[n][m] = sum_d a~[n][d] * b[m][d], K=256 (single fp16 both sides)
    gemm_tn<1><<<dim3(32, 32, 1), 256, 0, stream>>>(
        atp, 0, 256, 255, btp, 0, 256, 255, 256,
        nullptr, 0, Sbuf, Mru + p * 4096, Mcu + p * 4096);
    pv_part<<<dim3(64, 2, 4), 256, 0, stream>>>(
        aCb, bCb, Sbuf, Mru + p * 4096, Mcu + p * 4096, Ppart, Lp, p);
    pv_reduce<<<dim3(512), 256, 0, stream>>>(
        Ppart, Lp, out, out + 4194304, p);
  }
}

// Round 10
// 379.033 us; speedup vs baseline: 1.5053x; 1.5053x over previous
//
#include <hip/hip_runtime.h>
#include <stdint.h>

typedef unsigned short u16;
typedef unsigned int u32;
typedef _Float16 f16;
typedef float v4f __attribute__((ext_vector_type(4)));
typedef f16 v8h __attribute__((ext_vector_type(8)));

#define CC 256
#define NNN 4096

__device__ __forceinline__ u16 f2h(float f) {
  union { f16 h; u16 u; } c; c.h = (f16)f; return c.u;
}
// monotone float<->uint encoding for atomicMax on fp32
__device__ __forceinline__ u32 encf(float f) {
  u32 u = __float_as_uint(f);
  return (u >> 31) ? ~u : (u | 0x80000000u);
}
__device__ __forceinline__ float decf(u32 u) {
  return (u >> 31) ? __uint_as_float(u & 0x7fffffffu) : __uint_as_float(~u);
}
__device__ __forceinline__ void async16(const void* g, void* l) {
  __builtin_amdgcn_global_load_lds(
      (const __attribute__((address_space(1))) uint32_t*)g,
      (__attribute__((address_space(3))) uint32_t*)l, 16, 0, 0);
}

// ---- W [256][256] fp32 -> Ws [256][256] single fp16, K(c)-fast ----
__global__ __launch_bounds__(256) void wsplit(const float* __restrict__ W,
                                              u16* __restrict__ Ws) {
  const int d = blockIdx.x, c = threadIdx.x;
  Ws[d * 256 + c] = f2h(W[d * 256 + c]);
}

// ---- per batch: in [C][N] fp32 -> T [N][256] fp16 (transposed, K-fast),
//      and Cb [C][N] fp16 (straight copy) ----
__global__ __launch_bounds__(256) void tsplit(const float* __restrict__ in,
                                              u16* __restrict__ T,
                                              u16* __restrict__ Cb) {
  __shared__ u16 th[64][65];
  const int bb = blockIdx.z;
  const int n0 = blockIdx.x * 64;
  const int c0 = blockIdx.y * 64;
  const int tx = threadIdx.x & 63;
  const int ty = threadIdx.x >> 6;  // 0..3
  const float* ib = in + (size_t)bb * CC * NNN;
  u16* Tb = T + (size_t)bb * NNN * 256;
  u16* Cbb = Cb + (size_t)bb * CC * NNN;
#pragma unroll
  for (int k = 0; k < 16; k++) {
    int r = ty + k * 4;
    float v = ib[(size_t)(c0 + r) * NNN + n0 + tx];
    u16 h = f2h(v);
    th[r][tx] = h;
    Cbb[(size_t)(c0 + r) * NNN + n0 + tx] = h;
  }
  __syncthreads();
#pragma unroll
  for (int k = 0; k < 16; k++) {
    int r = ty + k * 4;
    Tb[(size_t)(n0 + r) * 256 + c0 + tx] = th[tx][r];
  }
}

// ---- TN GEMM over fp16, per-operand k-masking (legacy; both sides now
// run unmasked K=256). BK=64, XOR-swizzled LDS.
// MODE 0: out = a~ single fp16, pitch 256.
// MODE 1: out = S fp32 + row/col max atomics; tiles XCD-clustered.
template <int MODE>
__global__ __launch_bounds__(256) void gemm_tn(
    const u16* __restrict__ A, long sAb, int pa, int ma,
    const u16* __restrict__ Bm, long sBb, int pb, int mb, int ktot,
    u16* __restrict__ outb, long sOb, float* __restrict__ S,
    u32* __restrict__ Mru, u32* __restrict__ Mcu) {
  const int bz = blockIdx.z;
  const u16* Ab = A + (size_t)bz * sAb;
  const u16* Bb = Bm + (size_t)bz * sBb;
  int m0, n0;
  if (MODE == 0) {
    m0 = blockIdx.x * 128;
    n0 = blockIdx.y * 128;
  } else {
    const int bidl = blockIdx.x + (int)gridDim.x * blockIdx.y;  // 0..1023
    const int xcd = bidl & 7, idx = bidl >> 3;
    const int mt = (xcd & 3) * 8 + (idx & 7);
    const int nt = (xcd >> 2) * 16 + (idx >> 3);
    m0 = mt * 128;
    n0 = nt * 128;
  }
  const int tid = threadIdx.x;
  const int wave = tid >> 6;
  const int lane = tid & 63;
  const int q = lane >> 4;
  const int l = lane & 15;
  const int l7 = l & 7;
  const int wm = (wave >> 1) * 64;
  const int wn = (wave & 1) * 64;
  const int sr = lane >> 3;  // row-in-group 0..7
  const int sp = lane & 7;   // LDS chunk position 0..7
  const int sg = sp ^ sr;    // global chunk index (swizzle)

  __shared__ alignas(16) u16 sA[128 * 64];
  __shared__ alignas(16) u16 sB[128 * 64];

  v4f zero = {0.f, 0.f, 0.f, 0.f};
  v4f acc[4][4];
#pragma unroll
  for (int i = 0; i < 4; i++)
#pragma unroll
    for (int j = 0; j < 4; j++) acc[i][j] = zero;

  for (int k0 = 0; k0 < ktot; k0 += 64) {
    const int kA = k0 & ma;
    const int kB = k0 & mb;
    __syncthreads();
#pragma unroll
    for (int ii = 0; ii < 4; ii++) {
      int r = wave * 32 + ii * 8 + sr;
      async16(Ab + (size_t)(m0 + r) * pa + kA + sg * 8,
              &sA[r * 64 + sp * 8]);
    }
#pragma unroll
    for (int ii = 0; ii < 4; ii++) {
      int r = wave * 32 + ii * 8 + sr;
      async16(Bb + (size_t)(n0 + r) * pb + kB + sg * 8,
              &sB[r * 64 + sp * 8]);
    }
    __syncthreads();
#pragma unroll
    for (int s = 0; s < 2; s++) {
      const int pa8 = (s * 4 + q) ^ l7;
      v8h af[4], bfr[4];
#pragma unroll
      for (int i = 0; i < 4; i++)
        af[i] = *(const v8h*)&sA[(wm + i * 16 + l) * 64 + pa8 * 8];
#pragma unroll
      for (int j = 0; j < 4; j++)
        bfr[j] = *(const v8h*)&sB[(wn + j * 16 + l) * 64 + pa8 * 8];
#pragma unroll
      for (int i = 0; i < 4; i++)
#pragma unroll
        for (int j = 0; j < 4; j++)
          acc[i][j] = __builtin_amdgcn_mfma_f32_16x16x32_f16(af[i], bfr[j],
                                                             acc[i][j], 0, 0, 0);
    }
  }

  if (MODE == 0) {
    u16* ob = outb + (size_t)bz * sOb;
#pragma unroll
    for (int i = 0; i < 4; i++)
#pragma unroll
      for (int j = 0; j < 4; j++)
#pragma unroll
        for (int r = 0; r < 4; r++) {
          int row = m0 + wm + i * 16 + q * 4 + r;
          int col = n0 + wn + j * 16 + l;
          ob[(size_t)row * 256 + col] = f2h(acc[i][j][r]);
        }
  } else {
#pragma unroll
    for (int i = 0; i < 4; i++)
#pragma unroll
      for (int j = 0; j < 4; j++)
#pragma unroll
        for (int r = 0; r < 4; r++) {
          int row = m0 + wm + i * 16 + q * 4 + r;  // S row n
          int col = n0 + wn + j * 16 + l;          // S col m
          S[(size_t)row * NNN + col] = acc[i][j][r];
        }
    // --- row max (over this block's 128 cols) ---
    float rm[4][4];
#pragma unroll
    for (int i = 0; i < 4; i++)
#pragma unroll
      for (int r = 0; r < 4; r++)
        rm[i][r] = fmaxf(fmaxf(acc[i][0][r], acc[i][1][r]),
                         fmaxf(acc[i][2][r], acc[i][3][r]));
#pragma unroll
    for (int off = 1; off < 16; off <<= 1)
#pragma unroll
      for (int i = 0; i < 4; i++)
#pragma unroll
        for (int r = 0; r < 4; r++)
          rm[i][r] = fmaxf(rm[i][r], __shfl_xor(rm[i][r], off));
    if (l == 0) {
#pragma unroll
      for (int i = 0; i < 4; i++)
#pragma unroll
        for (int r = 0; r < 4; r++)
          atomicMax(&Mru[m0 + wm + i * 16 + q * 4 + r], encf(rm[i][r]));
    }
    // --- col max (over this block's 128 rows) ---
    float cm[4];
#pragma unroll
    for (int j = 0; j < 4; j++) {
      float v = -3e38f;
#pragma unroll
      for (int i = 0; i < 4; i++)
#pragma unroll
        for (int r = 0; r < 4; r++) v = fmaxf(v, acc[i][j][r]);
      cm[j] = v;
    }
#pragma unroll
    for (int off = 16; off < 64; off <<= 1)
#pragma unroll
      for (int j = 0; j < 4; j++) cm[j] = fmaxf(cm[j], __shfl_xor(cm[j], off));
    if (q == 0) {
#pragma unroll
      for (int j = 0; j < 4; j++)
        atomicMax(&Mcu[n0 + wn + j * 16 + l], encf(cm[j]));
    }
  }
}

// ---- K-split PV partial with fused L accumulation. fp16 V/P, BK=64,
// swizzled LDS, XCD-clustered (xcd -> (which,split)). R1/R8 baseline
// structure restored verbatim (R9's S-register-prefetch regressed:
// +32 live VGPRs across MFMA cost a resident block; the drain barrier
// forces S-load completion at the same point either way). ----
__global__ __launch_bounds__(256) void pv_part(
    const u16* __restrict__ aV, const u16* __restrict__ bV,
    const float* __restrict__ S, const u32* __restrict__ Mru,
    const u32* __restrict__ Mcu, float* __restrict__ part,
    float* __restrict__ Lp, int batch) {
  const int lin = blockIdx.x + 64 * (blockIdx.y + 2 * blockIdx.z);  // 0..511
  const int xcd = lin & 7;
  const int which = xcd & 1;
  const int split = xcd >> 1;
  const int x0 = (lin >> 3) * 64;
  const u16* Av = (which ? bV : aV) + (size_t)batch * (CC * NNN);
  const u32* Mst = which ? Mru : Mcu;
  float* Out = part + ((size_t)split * 2 + which) * (CC * NNN);
  float* Lpo = Lp + ((size_t)split * 2 + which) * NNN;

  const int tid = threadIdx.x;
  const int wave = tid >> 6, lane = tid & 63, q = lane >> 4, l = lane & 15;
  const int l7 = l & 7;
  const int sr = lane >> 3, sp = lane & 7, sg = sp ^ sr;
  // which=1 S-read coords: 64 x-rows x 4 chunks of 16 k
  const int xl = tid >> 2, ch = tid & 3;
  // which=0 S-read coords: 64 x-cols x 4 groups of 16 k-rows
  const int xs = tid & 63, kq = (tid >> 6) * 16;

  __shared__ alignas(16) u16 sA[256 * 64];
  __shared__ alignas(16) u16 sB[64 * 64];
  __shared__ float lsh[256];

  v4f zero = {0.f, 0.f, 0.f, 0.f};
  v4f acc[4][4];
#pragma unroll
  for (int i = 0; i < 4; i++)
#pragma unroll
    for (int j = 0; j < 4; j++) acc[i][j] = zero;

  const float mx = decf(Mst[x0 + (which ? xl : xs)]);
  float lsum = 0.f;
  const int kbeg = split * 1024;

  for (int k0 = kbeg; k0 < kbeg + 1024; k0 += 64) {
    __syncthreads();
#pragma unroll
    for (int ii = 0; ii < 8; ii++) {
      int r = wave * 64 + ii * 8 + sr;
      async16(Av + (size_t)r * NNN + k0 + sg * 8, &sA[r * 64 + sp * 8]);
    }
    if (which) {
      const float* gp = S + (size_t)(x0 + xl) * NNN + k0 + ch * 16;
      float e[16];
#pragma unroll
      for (int t4 = 0; t4 < 4; t4++) {
        float4 v = ((const float4*)gp)[t4];
        e[t4 * 4 + 0] = __expf(v.x - mx);
        e[t4 * 4 + 1] = __expf(v.y - mx);
        e[t4 * 4 + 2] = __expf(v.z - mx);
        e[t4 * 4 + 3] = __expf(v.w - mx);
      }
#pragma unroll
      for (int t = 0; t < 16; t++) lsum += e[t];
      v8h pk0, pk1;
#pragma unroll
      for (int t = 0; t < 8; t++) {
        pk0[t] = (f16)e[t];
        pk1[t] = (f16)e[t + 8];
      }
      const int g0 = ch * 2;
      *(v8h*)&sB[xl * 64 + (g0 ^ (xl & 7)) * 8] = pk0;
      *(v8h*)&sB[xl * 64 + ((g0 + 1) ^ (xl & 7)) * 8] = pk1;
    } else {
      const float* gp = S + (size_t)(k0 + kq) * NNN + x0 + xs;
      float e[16];
#pragma unroll
      for (int t = 0; t < 16; t++)
        e[t] = __expf(gp[(size_t)t * NNN] - mx);
#pragma unroll
      for (int t = 0; t < 16; t++) lsum += e[t];
      v8h pk0, pk1;
#pragma unroll
      for (int t = 0; t < 8; t++) {
        pk0[t] = (f16)e[t];
        pk1[t] = (f16)e[t + 8];
      }
      const int g0 = (tid >> 6) * 2;
      *(v8h*)&sB[xs * 64 + (g0 ^ (xs & 7)) * 8] = pk0;
      *(v8h*)&sB[xs * 64 + ((g0 + 1) ^ (xs & 7)) * 8] = pk1;
    }
    __syncthreads();
#pragma unroll
    for (int s = 0; s < 2; s++) {
      const int pa8 = (s * 4 + q) ^ l7;
      v8h af[4], bfr[4];
#pragma unroll
      for (int i = 0; i < 4; i++)
        af[i] = *(const v8h*)&sA[(wave * 64 + i * 16 + l) * 64 + pa8 * 8];
#pragma unroll
      for (int j = 0; j < 4; j++)
        bfr[j] = *(const v8h*)&sB[(j * 16 + l) * 64 + pa8 * 8];
#pragma unroll
      for (int i = 0; i < 4; i++)
#pragma unroll
        for (int j = 0; j < 4; j++)
          acc[i][j] = __builtin_amdgcn_mfma_f32_16x16x32_f16(af[i], bfr[j],
                                                             acc[i][j], 0, 0, 0);
    }
  }

  // L partial reduction: 4 threads contribute per x
  __syncthreads();
  lsh[tid] = lsum;
  __syncthreads();
  if (tid < 64) {
    float t;
    if (which)
      t = (lsh[tid * 4] + lsh[tid * 4 + 1]) + (lsh[tid * 4 + 2] + lsh[tid * 4 + 3]);
    else
      t = (lsh[tid] + lsh[tid + 64]) + (lsh[tid + 128] + lsh[tid + 192]);
    Lpo[x0 + tid] = t;
  }

#pragma unroll
  for (int i = 0; i < 4; i++)
#pragma unroll
    for (int j = 0; j < 4; j++)
#pragma unroll
      for (int r = 0; r < 4; r++) {
        int c = wave * 64 + i * 16 + q * 4 + r;
        int x = x0 + j * 16 + l;
        Out[(size_t)c * NNN + x] = acc[i][j][r];
      }
}

// ---- reduce 4 K-split partials + L partials, apply 1/L, write output ----
__global__ __launch_bounds__(256) void pv_reduce(
    const float* __restrict__ part, const float* __restrict__ Lp,
    float* __restrict__ outA, float* __restrict__ outB, int batch) {
  const int bi = blockIdx.x;  // 0..511
  const int which = bi >> 8;
  const int c = bi & 255;
  float* Out = (which ? outB : outA) + (size_t)batch * CC * NNN +
               (size_t)c * NNN;
  const float* p0 = part + (size_t)which * (CC * NNN) + (size_t)c * NNN;
  const float* l0 = Lp + (size_t)which * NNN;
  const size_t ps = 2 * (size_t)CC * NNN;
  const size_t ls = 2 * (size_t)NNN;
  const int t = threadIdx.x;
#pragma unroll
  for (int xi = 0; xi < 4; xi++) {
    int x = xi * 1024 + t * 4;
    float4 a0 = *(const float4*)(p0 + x);
    float4 a1 = *(const float4*)(p0 + ps + x);
    float4 a2 = *(const float4*)(p0 + 2 * ps + x);
    float4 a3 = *(const float4*)(p0 + 3 * ps + x);
    float4 q0 = *(const float4*)(l0 + x);
    float4 q1 = *(const float4*)(l0 + ls + x);
    float4 q2 = *(const float4*)(l0 + 2 * ls + x);
    float4 q3 = *(const float4*)(l0 + 3 * ls + x);
    float4 o;
    o.x = ((a0.x + a1.x) + (a2.x + a3.x)) / ((q0.x + q1.x) + (q2.x + q3.x));
    o.y = ((a0.y + a1.y) + (a2.y + a3.y)) / ((q0.y + q1.y) + (q2.y + q3.y));
    o.z = ((a0.z + a1.z) + (a2.z + a3.z)) / ((q0.z + q1.z) + (q2.z + q3.z));
    o.w = ((a0.w + a1.w) + (a2.w + a3.w)) / ((q0.w + q1.w) + (q2.w + q3.w));
    *(float4*)(Out + x) = o;
  }
}

extern "C" void kernel_launch(void* const* d_in, const int* in_sizes, int n_in,
                              void* d_out, int out_size, void* d_ws,
                              size_t ws_size, hipStream_t stream) {
  const float* a = (const float*)d_in[0];
  const float* b = (const float*)d_in[1];
  const float* W = (const float*)d_in[2];
  float* out = (float*)d_out;

  char* ws = (char*)d_ws;
  u16* Ws = (u16*)(ws);                     // 131072 (256KB rsvd)
  u16* aT = (u16*)(ws + 262144);            // 4*4096*256*2 = 8388608
  u16* bT = (u16*)(ws + 8650752);           // 8388608
  u16* aCb = (u16*)(ws + 17039360);         // 8388608
  u16* bCb = (u16*)(ws + 25427968);         // 8388608
  u16* ats = (u16*)(ws + 33816576);         // 4*4096*256*2 = 8388608 (16MB rsvd)
  u32* Mru = (u32*)(ws + 50593792);         // [4][4096] u32 = 65536
  u32* Mcu = (u32*)(ws + 50659328);         // 65536
  float* Lp = (float*)(ws + 50724864);      // 131072
  float* Sbuf = (float*)(ws + 50855936);    // 67108864
  float* Ppart = (float*)(ws + 117964800);  // 33554432 -> ends ~151.5 MB

  wsplit<<<dim3(256), 256, 0, stream>>>(W, Ws);
  tsplit<<<dim3(64, 4, 4), 256, 0, stream>>>(a, aT, aCb);
  tsplit<<<dim3(64, 4, 4), 256, 0, stream>>>(b, bT, bCb);
  // a~[n][d] = sum_c aT[n][c] * W[d][c], K=256 single fp16 both sides,
  // output single fp16, pitch 256
  gemm_tn<0><<<dim3(32, 2, 4), 256, 0, stream>>>(
      aT, (long)NNN * 256, 256, 255, Ws, 0, 256, 255, 256,
      ats, (long)NNN * 256, nullptr, nullptr, nullptr);
  hipMemsetAsync(Mru, 0, 131072, stream);  // all 4 batches' Mru+Mcu

  for (int p = 0; p < 4; p++) {
    const u16* atp = ats + (size_t)p * NNN * 256;
    const u16* btp = bT + (size_t)p * NNN * 256;
    // S[n][m] = sum_d a~[n][d] * b[m][d], K=256 (single fp16 both sides)
    gemm_tn<1><<<dim3(32, 32, 1), 256, 0, stream>>>(
        atp, 0, 256, 255, btp, 0, 256, 255, 256,
        nullptr, 0, Sbuf, Mru + p * 4096, Mcu + p * 4096);
    pv_part<<<dim3(64, 2, 4), 256, 0, stream>>>(
        aCb, bCb, Sbuf, Mru + p * 4096, Mcu + p * 4096, Ppart, Lp, p);
    pv_reduce<<<dim3(512), 256, 0, stream>>>(
        Ppart, Lp, out, out + 4194304, p);
  }
}

// Round 11
// 364.596 us; speedup vs baseline: 1.5649x; 1.0396x over previous
//
#include <hip/hip_runtime.h>
#include <stdint.h>

typedef unsigned short u16;
typedef unsigned int u32;
typedef _Float16 f16;
typedef float v4f __attribute__((ext_vector_type(4)));
typedef f16 v8h __attribute__((ext_vector_type(8)));

#define CC 256
#define NNN 4096

__device__ __forceinline__ u16 f2h(float f) {
  union { f16 h; u16 u; } c; c.h = (f16)f; return c.u;
}
// monotone float<->uint encoding for atomicMax on fp32
__device__ __forceinline__ u32 encf(float f) {
  u32 u = __float_as_uint(f);
  return (u >> 31) ? ~u : (u | 0x80000000u);
}
__device__ __forceinline__ float decf(u32 u) {
  return (u >> 31) ? __uint_as_float(u & 0x7fffffffu) : __uint_as_float(~u);
}
__device__ __forceinline__ void async16(const void* g, void* l) {
  __builtin_amdgcn_global_load_lds(
      (const __attribute__((address_space(1))) uint32_t*)g,
      (__attribute__((address_space(3))) uint32_t*)l, 16, 0, 0);
}

// ---- W [256][256] fp32 -> Ws [256][256] single fp16, K(c)-fast ----
__global__ __launch_bounds__(256) void wsplit(const float* __restrict__ W,
                                              u16* __restrict__ Ws) {
  const int d = blockIdx.x, c = threadIdx.x;
  Ws[d * 256 + c] = f2h(W[d * 256 + c]);
}

// ---- per batch: in [C][N] fp32 -> T [N][256] fp16 (transposed, K-fast),
//      and Cb [C][N] fp16 (straight copy) ----
__global__ __launch_bounds__(256) void tsplit(const float* __restrict__ in,
                                              u16* __restrict__ T,
                                              u16* __restrict__ Cb) {
  __shared__ u16 th[64][65];
  const int bb = blockIdx.z;
  const int n0 = blockIdx.x * 64;
  const int c0 = blockIdx.y * 64;
  const int tx = threadIdx.x & 63;
  const int ty = threadIdx.x >> 6;  // 0..3
  const float* ib = in + (size_t)bb * CC * NNN;
  u16* Tb = T + (size_t)bb * NNN * 256;
  u16* Cbb = Cb + (size_t)bb * CC * NNN;
#pragma unroll
  for (int k = 0; k < 16; k++) {
    int r = ty + k * 4;
    float v = ib[(size_t)(c0 + r) * NNN + n0 + tx];
    u16 h = f2h(v);
    th[r][tx] = h;
    Cbb[(size_t)(c0 + r) * NNN + n0 + tx] = h;
  }
  __syncthreads();
#pragma unroll
  for (int k = 0; k < 16; k++) {
    int r = ty + k * 4;
    Tb[(size_t)(n0 + r) * 256 + c0 + tx] = th[tx][r];
  }
}

// ---- TN GEMM over fp16, per-operand k-masking (legacy; both sides now
// run unmasked K=256). BK=64, XOR-swizzled LDS.
// MODE 0: out = a~ single fp16, pitch 256.
// MODE 1: out = S fp16 (halves S HBM traffic both directions; rounding
//   error |S|*2^-11 is same magnitude as the R8 a~ rounding, which moved
//   absmax only 0.031->0.039) + row/col max atomics (fp32-accurate).
template <int MODE>
__global__ __launch_bounds__(256) void gemm_tn(
    const u16* __restrict__ A, long sAb, int pa, int ma,
    const u16* __restrict__ Bm, long sBb, int pb, int mb, int ktot,
    u16* __restrict__ outb, long sOb, u16* __restrict__ S,
    u32* __restrict__ Mru, u32* __restrict__ Mcu) {
  const int bz = blockIdx.z;
  const u16* Ab = A + (size_t)bz * sAb;
  const u16* Bb = Bm + (size_t)bz * sBb;
  int m0, n0;
  if (MODE == 0) {
    m0 = blockIdx.x * 128;
    n0 = blockIdx.y * 128;
  } else {
    const int bidl = blockIdx.x + (int)gridDim.x * blockIdx.y;  // 0..1023
    const int xcd = bidl & 7, idx = bidl >> 3;
    const int mt = (xcd & 3) * 8 + (idx & 7);
    const int nt = (xcd >> 2) * 16 + (idx >> 3);
    m0 = mt * 128;
    n0 = nt * 128;
  }
  const int tid = threadIdx.x;
  const int wave = tid >> 6;
  const int lane = tid & 63;
  const int q = lane >> 4;
  const int l = lane & 15;
  const int l7 = l & 7;
  const int wm = (wave >> 1) * 64;
  const int wn = (wave & 1) * 64;
  const int sr = lane >> 3;  // row-in-group 0..7
  const int sp = lane & 7;   // LDS chunk position 0..7
  const int sg = sp ^ sr;    // global chunk index (swizzle)

  __shared__ alignas(16) u16 sA[128 * 64];
  __shared__ alignas(16) u16 sB[128 * 64];

  v4f zero = {0.f, 0.f, 0.f, 0.f};
  v4f acc[4][4];
#pragma unroll
  for (int i = 0; i < 4; i++)
#pragma unroll
    for (int j = 0; j < 4; j++) acc[i][j] = zero;

  for (int k0 = 0; k0 < ktot; k0 += 64) {
    const int kA = k0 & ma;
    const int kB = k0 & mb;
    __syncthreads();
#pragma unroll
    for (int ii = 0; ii < 4; ii++) {
      int r = wave * 32 + ii * 8 + sr;
      async16(Ab + (size_t)(m0 + r) * pa + kA + sg * 8,
              &sA[r * 64 + sp * 8]);
    }
#pragma unroll
    for (int ii = 0; ii < 4; ii++) {
      int r = wave * 32 + ii * 8 + sr;
      async16(Bb + (size_t)(n0 + r) * pb + kB + sg * 8,
              &sB[r * 64 + sp * 8]);
    }
    __syncthreads();
#pragma unroll
    for (int s = 0; s < 2; s++) {
      const int pa8 = (s * 4 + q) ^ l7;
      v8h af[4], bfr[4];
#pragma unroll
      for (int i = 0; i < 4; i++)
        af[i] = *(const v8h*)&sA[(wm + i * 16 + l) * 64 + pa8 * 8];
#pragma unroll
      for (int j = 0; j < 4; j++)
        bfr[j] = *(const v8h*)&sB[(wn + j * 16 + l) * 64 + pa8 * 8];
#pragma unroll
      for (int i = 0; i < 4; i++)
#pragma unroll
        for (int j = 0; j < 4; j++)
          acc[i][j] = __builtin_amdgcn_mfma_f32_16x16x32_f16(af[i], bfr[j],
                                                             acc[i][j], 0, 0, 0);
    }
  }

  if (MODE == 0) {
    u16* ob = outb + (size_t)bz * sOb;
#pragma unroll
    for (int i = 0; i < 4; i++)
#pragma unroll
      for (int j = 0; j < 4; j++)
#pragma unroll
        for (int r = 0; r < 4; r++) {
          int row = m0 + wm + i * 16 + q * 4 + r;
          int col = n0 + wn + j * 16 + l;
          ob[(size_t)row * 256 + col] = f2h(acc[i][j][r]);
        }
  } else {
#pragma unroll
    for (int i = 0; i < 4; i++)
#pragma unroll
      for (int j = 0; j < 4; j++)
#pragma unroll
        for (int r = 0; r < 4; r++) {
          int row = m0 + wm + i * 16 + q * 4 + r;  // S row n
          int col = n0 + wn + j * 16 + l;          // S col m
          S[(size_t)row * NNN + col] = f2h(acc[i][j][r]);
        }
    // --- row max (over this block's 128 cols) ---
    float rm[4][4];
#pragma unroll
    for (int i = 0; i < 4; i++)
#pragma unroll
      for (int r = 0; r < 4; r++)
        rm[i][r] = fmaxf(fmaxf(acc[i][0][r], acc[i][1][r]),
                         fmaxf(acc[i][2][r], acc[i][3][r]));
#pragma unroll
    for (int off = 1; off < 16; off <<= 1)
#pragma unroll
      for (int i = 0; i < 4; i++)
#pragma unroll
        for (int r = 0; r < 4; r++)
          rm[i][r] = fmaxf(rm[i][r], __shfl_xor(rm[i][r], off));
    if (l == 0) {
#pragma unroll
      for (int i = 0; i < 4; i++)
#pragma unroll
        for (int r = 0; r < 4; r++)
          atomicMax(&Mru[m0 + wm + i * 16 + q * 4 + r], encf(rm[i][r]));
    }
    // --- col max (over this block's 128 rows) ---
    float cm[4];
#pragma unroll
    for (int j = 0; j < 4; j++) {
      float v = -3e38f;
#pragma unroll
      for (int i = 0; i < 4; i++)
#pragma unroll
        for (int r = 0; r < 4; r++) v = fmaxf(v, acc[i][j][r]);
      cm[j] = v;
    }
#pragma unroll
    for (int off = 16; off < 64; off <<= 1)
#pragma unroll
      for (int j = 0; j < 4; j++) cm[j] = fmaxf(cm[j], __shfl_xor(cm[j], off));
    if (q == 0) {
#pragma unroll
      for (int j = 0; j < 4; j++)
        atomicMax(&Mcu[n0 + wn + j * 16 + l], encf(cm[j]));
    }
  }
}

// ---- K-split PV partial with fused L accumulation. fp16 V/P/S, BK=64,
// swizzled LDS, XCD-clustered (xcd -> (which,split)). Baseline loop
// structure; S now read as fp16 (half the FETCH bytes). ----
__global__ __launch_bounds__(256) void pv_part(
    const u16* __restrict__ aV, const u16* __restrict__ bV,
    const u16* __restrict__ S, const u32* __restrict__ Mru,
    const u32* __restrict__ Mcu, float* __restrict__ part,
    float* __restrict__ Lp, int batch) {
  const int lin = blockIdx.x + 64 * (blockIdx.y + 2 * blockIdx.z);  // 0..511
  const int xcd = lin & 7;
  const int which = xcd & 1;
  const int split = xcd >> 1;
  const int x0 = (lin >> 3) * 64;
  const u16* Av = (which ? bV : aV) + (size_t)batch * (CC * NNN);
  const u32* Mst = which ? Mru : Mcu;
  float* Out = part + ((size_t)split * 2 + which) * (CC * NNN);
  float* Lpo = Lp + ((size_t)split * 2 + which) * NNN;

  const int tid = threadIdx.x;
  const int wave = tid >> 6, lane = tid & 63, q = lane >> 4, l = lane & 15;
  const int l7 = l & 7;
  const int sr = lane >> 3, sp = lane & 7, sg = sp ^ sr;
  // which=1 S-read coords: 64 x-rows x 4 chunks of 16 k
  const int xl = tid >> 2, ch = tid & 3;
  // which=0 S-read coords: 64 x-cols x 4 groups of 16 k-rows
  const int xs = tid & 63, kq = (tid >> 6) * 16;

  __shared__ alignas(16) u16 sA[256 * 64];
  __shared__ alignas(16) u16 sB[64 * 64];
  __shared__ float lsh[256];

  v4f zero = {0.f, 0.f, 0.f, 0.f};
  v4f acc[4][4];
#pragma unroll
  for (int i = 0; i < 4; i++)
#pragma unroll
    for (int j = 0; j < 4; j++) acc[i][j] = zero;

  const float mx = decf(Mst[x0 + (which ? xl : xs)]);
  float lsum = 0.f;
  const int kbeg = split * 1024;

  for (int k0 = kbeg; k0 < kbeg + 1024; k0 += 64) {
    __syncthreads();
#pragma unroll
    for (int ii = 0; ii < 8; ii++) {
      int r = wave * 64 + ii * 8 + sr;
      async16(Av + (size_t)r * NNN + k0 + sg * 8, &sA[r * 64 + sp * 8]);
    }
    if (which) {
      const u16* gp = S + (size_t)(x0 + xl) * NNN + k0 + ch * 16;
      v8h h0 = *(const v8h*)gp;
      v8h h1 = *(const v8h*)(gp + 8);
      float e[16];
#pragma unroll
      for (int t = 0; t < 8; t++) {
        e[t] = __expf((float)h0[t] - mx);
        e[t + 8] = __expf((float)h1[t] - mx);
      }
#pragma unroll
      for (int t = 0; t < 16; t++) lsum += e[t];
      v8h pk0, pk1;
#pragma unroll
      for (int t = 0; t < 8; t++) {
        pk0[t] = (f16)e[t];
        pk1[t] = (f16)e[t + 8];
      }
      const int g0 = ch * 2;
      *(v8h*)&sB[xl * 64 + (g0 ^ (xl & 7)) * 8] = pk0;
      *(v8h*)&sB[xl * 64 + ((g0 + 1) ^ (xl & 7)) * 8] = pk1;
    } else {
      const u16* gp = S + (size_t)(k0 + kq) * NNN + x0 + xs;
      float e[16];
#pragma unroll
      for (int t = 0; t < 16; t++)
        e[t] = __expf((float)(*(const f16*)&gp[(size_t)t * NNN]) - mx);
#pragma unroll
      for (int t = 0; t < 16; t++) lsum += e[t];
      v8h pk0, pk1;
#pragma unroll
      for (int t = 0; t < 8; t++) {
        pk0[t] = (f16)e[t];
        pk1[t] = (f16)e[t + 8];
      }
      const int g0 = (tid >> 6) * 2;
      *(v8h*)&sB[xs * 64 + (g0 ^ (xs & 7)) * 8] = pk0;
      *(v8h*)&sB[xs * 64 + ((g0 + 1) ^ (xs & 7)) * 8] = pk1;
    }
    __syncthreads();
#pragma unroll
    for (int s = 0; s < 2; s++) {
      const int pa8 = (s * 4 + q) ^ l7;
      v8h af[4], bfr[4];
#pragma unroll
      for (int i = 0; i < 4; i++)
        af[i] = *(const v8h*)&sA[(wave * 64 + i * 16 + l) * 64 + pa8 * 8];
#pragma unroll
      for (int j = 0; j < 4; j++)
        bfr[j] = *(const v8h*)&sB[(j * 16 + l) * 64 + pa8 * 8];
#pragma unroll
      for (int i = 0; i < 4; i++)
#pragma unroll
        for (int j = 0; j < 4; j++)
          acc[i][j] = __builtin_amdgcn_mfma_f32_16x16x32_f16(af[i], bfr[j],
                                                             acc[i][j], 0, 0, 0);
    }
  }

  // L partial reduction: 4 threads contribute per x
  __syncthreads();
  lsh[tid] = lsum;
  __syncthreads();
  if (tid < 64) {
    float t;
    if (which)
      t = (lsh[tid * 4] + lsh[tid * 4 + 1]) + (lsh[tid * 4 + 2] + lsh[tid * 4 + 3]);
    else
      t = (lsh[tid] + lsh[tid + 64]) + (lsh[tid + 128] + lsh[tid + 192]);
    Lpo[x0 + tid] = t;
  }

#pragma unroll
  for (int i = 0; i < 4; i++)
#pragma unroll
    for (int j = 0; j < 4; j++)
#pragma unroll
      for (int r = 0; r < 4; r++) {
        int c = wave * 64 + i * 16 + q * 4 + r;
        int x = x0 + j * 16 + l;
        Out[(size_t)c * NNN + x] = acc[i][j][r];
      }
}

// ---- reduce 4 K-split partials + L partials, apply 1/L, write output ----
__global__ __launch_bounds__(256) void pv_reduce(
    const float* __restrict__ part, const float* __restrict__ Lp,
    float* __restrict__ outA, float* __restrict__ outB, int batch) {
  const int bi = blockIdx.x;  // 0..511
  const int which = bi >> 8;
  const int c = bi & 255;
  float* Out = (which ? outB : outA) + (size_t)batch * CC * NNN +
               (size_t)c * NNN;
  const float* p0 = part + (size_t)which * (CC * NNN) + (size_t)c * NNN;
  const float* l0 = Lp + (size_t)which * NNN;
  const size_t ps = 2 * (size_t)CC * NNN;
  const size_t ls = 2 * (size_t)NNN;
  const int t = threadIdx.x;
#pragma unroll
  for (int xi = 0; xi < 4; xi++) {
    int x = xi * 1024 + t * 4;
    float4 a0 = *(const float4*)(p0 + x);
    float4 a1 = *(const float4*)(p0 + ps + x);
    float4 a2 = *(const float4*)(p0 + 2 * ps + x);
    float4 a3 = *(const float4*)(p0 + 3 * ps + x);
    float4 q0 = *(const float4*)(l0 + x);
    float4 q1 = *(const float4*)(l0 + ls + x);
    float4 q2 = *(const float4*)(l0 + 2 * ls + x);
    float4 q3 = *(const float4*)(l0 + 3 * ls + x);
    float4 o;
    o.x = ((a0.x + a1.x) + (a2.x + a3.x)) / ((q0.x + q1.x) + (q2.x + q3.x));
    o.y = ((a0.y + a1.y) + (a2.y + a3.y)) / ((q0.y + q1.y) + (q2.y + q3.y));
    o.z = ((a0.z + a1.z) + (a2.z + a3.z)) / ((q0.z + q1.z) + (q2.z + q3.z));
    o.w = ((a0.w + a1.w) + (a2.w + a3.w)) / ((q0.w + q1.w) + (q2.w + q3.w));
    *(float4*)(Out + x) = o;
  }
}

extern "C" void kernel_launch(void* const* d_in, const int* in_sizes, int n_in,
                              void* d_out, int out_size, void* d_ws,
                              size_t ws_size, hipStream_t stream) {
  const float* a = (const float*)d_in[0];
  const float* b = (const float*)d_in[1];
  const float* W = (const float*)d_in[2];
  float* out = (float*)d_out;

  char* ws = (char*)d_ws;
  u16* Ws = (u16*)(ws);                     // 131072 (256KB rsvd)
  u16* aT = (u16*)(ws + 262144);            // 4*4096*256*2 = 8388608
  u16* bT = (u16*)(ws + 8650752);           // 8388608
  u16* aCb = (u16*)(ws + 17039360);         // 8388608
  u16* bCb = (u16*)(ws + 25427968);         // 8388608
  u16* ats = (u16*)(ws + 33816576);         // 4*4096*256*2 = 8388608 (16MB rsvd)
  u32* Mru = (u32*)(ws + 50593792);         // [4][4096] u32 = 65536
  u32* Mcu = (u32*)(ws + 50659328);         // 65536
  float* Lp = (float*)(ws + 50724864);      // 131072
  u16* Sbuf = (u16*)(ws + 50855936);        // S fp16: 33554432
  float* Ppart = (float*)(ws + 117964800);  // 33554432 -> ends ~151.5 MB

  wsplit<<<dim3(256), 256, 0, stream>>>(W, Ws);
  tsplit<<<dim3(64, 4, 4), 256, 0, stream>>>(a, aT, aCb);
  tsplit<<<dim3(64, 4, 4), 256, 0, stream>>>(b, bT, bCb);
  // a~[n][d] = sum_c aT[n][c] * W[d][c], K=256 single fp16 both sides,
  // output single fp16, pitch 256
  gemm_tn<0><<<dim3(32, 2, 4), 256, 0, stream>>>(
      aT, (long)NNN * 256, 256, 255, Ws, 0, 256, 255, 256,
      ats, (long)NNN * 256, nullptr, nullptr, nullptr);
  hipMemsetAsync(Mru, 0, 131072, stream);  // all 4 batches' Mru+Mcu

  for (int p = 0; p < 4; p++) {
    const u16* atp = ats + (size_t)p * NNN * 256;
    const u16* btp = bT + (size_t)p * NNN * 256;
    // S[n][m] = sum_d a~[n][d] * b[m][d], K=256, S stored fp16
    gemm_tn<1><<<dim3(32, 32, 1), 256, 0, stream>>>(
        atp, 0, 256, 255, btp, 0, 256, 255, 256,
        nullptr, 0, Sbuf, Mru + p * 4096, Mcu + p * 4096);
    pv_part<<<dim3(64, 2, 4), 256, 0, stream>>>(
        aCb, bCb, Sbuf, Mru + p * 4096, Mcu + p * 4096, Ppart, Lp, p);
    pv_reduce<<<dim3(512), 256, 0, stream>>>(
        Ppart, Lp, out, out + 4194304, p);
  }
}

// Round 12
// 322.020 us; speedup vs baseline: 1.7718x; 1.1322x over previous
//
#include <hip/hip_runtime.h>
#include <stdint.h>

typedef unsigned short u16;
typedef unsigned int u32;
typedef _Float16 f16;
typedef float v4f __attribute__((ext_vector_type(4)));
typedef f16 v8h __attribute__((ext_vector_type(8)));

#define CC 256
#define NNN 4096

__device__ __forceinline__ u16 f2h(float f) {
  union { f16 h; u16 u; } c; c.h = (f16)f; return c.u;
}
__device__ __forceinline__ float h2f(u16 u) {
  union { f16 h; u16 u; } c; c.u = u; return (float)c.h;
}
// monotone float<->uint encoding for atomicMax on fp32
__device__ __forceinline__ u32 encf(float f) {
  u32 u = __float_as_uint(f);
  return (u >> 31) ? ~u : (u | 0x80000000u);
}
__device__ __forceinline__ float decf(u32 u) {
  return (u >> 31) ? __uint_as_float(u & 0x7fffffffu) : __uint_as_float(~u);
}
__device__ __forceinline__ void async16(const void* g, void* l) {
  __builtin_amdgcn_global_load_lds(
      (const __attribute__((address_space(1))) uint32_t*)g,
      (__attribute__((address_space(3))) uint32_t*)l, 16, 0, 0);
}

// ---- W [256][256] fp32 -> Ws [256][256] single fp16, K(c)-fast ----
__global__ __launch_bounds__(256) void wsplit(const float* __restrict__ W,
                                              u16* __restrict__ Ws) {
  const int d = blockIdx.x, c = threadIdx.x;
  Ws[d * 256 + c] = f2h(W[d * 256 + c]);
}

// ---- both inputs, all batches: in [C][N] fp32 -> T [N][256] fp16
// (transposed) and Cb [C][N] fp16 copy. z = batch(0..3) | which<<2. ----
__global__ __launch_bounds__(256) void tsplit(
    const float* __restrict__ asrc, const float* __restrict__ bsrc,
    u16* __restrict__ aT, u16* __restrict__ bT,
    u16* __restrict__ aCb, u16* __restrict__ bCb) {
  __shared__ u16 th[64][65];
  const int bz = blockIdx.z;
  const int bb = bz & 3;
  const int wh = bz >> 2;
  const int n0 = blockIdx.x * 64;
  const int c0 = blockIdx.y * 64;
  const int tx = threadIdx.x & 63;
  const int ty = threadIdx.x >> 6;  // 0..3
  const float* ib = (wh ? bsrc : asrc) + (size_t)bb * CC * NNN;
  u16* Tb = (wh ? bT : aT) + (size_t)bb * NNN * 256;
  u16* Cbb = (wh ? bCb : aCb) + (size_t)bb * CC * NNN;
#pragma unroll
  for (int k = 0; k < 16; k++) {
    int r = ty + k * 4;
    float v = ib[(size_t)(c0 + r) * NNN + n0 + tx];
    u16 h = f2h(v);
    th[r][tx] = h;
    Cbb[(size_t)(c0 + r) * NNN + n0 + tx] = h;
  }
  __syncthreads();
#pragma unroll
  for (int k = 0; k < 16; k++) {
    int r = ty + k * 4;
    Tb[(size_t)(n0 + r) * 256 + c0 + tx] = th[tx][r];
  }
}

// ---- TN GEMM over fp16, K=256. BK=64, XOR-swizzled LDS.
// MODE 0: out = a~ single fp16, pitch 256.
// MODE 1: out = S fp16 + row/col max atomics; per-z batch slabs;
//         tiles XCD-clustered in xy.
template <int MODE>
__global__ __launch_bounds__(256) void gemm_tn(
    const u16* __restrict__ A, long sAb, int pa, int ma,
    const u16* __restrict__ Bm, long sBb, int pb, int mb, int ktot,
    u16* __restrict__ outb, long sOb, u16* __restrict__ S,
    u32* __restrict__ Mru, u32* __restrict__ Mcu) {
  const int bz = blockIdx.z;
  const u16* Ab = A + (size_t)bz * sAb;
  const u16* Bb = Bm + (size_t)bz * sBb;
  int m0, n0;
  if (MODE == 0) {
    m0 = blockIdx.x * 128;
    n0 = blockIdx.y * 128;
  } else {
    const int bidl = blockIdx.x + (int)gridDim.x * blockIdx.y;  // 0..1023
    const int xcd = bidl & 7, idx = bidl >> 3;
    const int mt = (xcd & 3) * 8 + (idx & 7);
    const int nt = (xcd >> 2) * 16 + (idx >> 3);
    m0 = mt * 128;
    n0 = nt * 128;
  }
  const int tid = threadIdx.x;
  const int wave = tid >> 6;
  const int lane = tid & 63;
  const int q = lane >> 4;
  const int l = lane & 15;
  const int l7 = l & 7;
  const int wm = (wave >> 1) * 64;
  const int wn = (wave & 1) * 64;
  const int sr = lane >> 3;  // row-in-group 0..7
  const int sp = lane & 7;   // LDS chunk position 0..7
  const int sg = sp ^ sr;    // global chunk index (swizzle)

  __shared__ alignas(16) u16 sA[128 * 64];
  __shared__ alignas(16) u16 sB[128 * 64];

  v4f zero = {0.f, 0.f, 0.f, 0.f};
  v4f acc[4][4];
#pragma unroll
  for (int i = 0; i < 4; i++)
#pragma unroll
    for (int j = 0; j < 4; j++) acc[i][j] = zero;

  for (int k0 = 0; k0 < ktot; k0 += 64) {
    const int kA = k0 & ma;
    const int kB = k0 & mb;
    __syncthreads();
#pragma unroll
    for (int ii = 0; ii < 4; ii++) {
      int r = wave * 32 + ii * 8 + sr;
      async16(Ab + (size_t)(m0 + r) * pa + kA + sg * 8,
              &sA[r * 64 + sp * 8]);
    }
#pragma unroll
    for (int ii = 0; ii < 4; ii++) {
      int r = wave * 32 + ii * 8 + sr;
      async16(Bb + (size_t)(n0 + r) * pb + kB + sg * 8,
              &sB[r * 64 + sp * 8]);
    }
    __syncthreads();
#pragma unroll
    for (int s = 0; s < 2; s++) {
      const int pa8 = (s * 4 + q) ^ l7;
      v8h af[4], bfr[4];
#pragma unroll
      for (int i = 0; i < 4; i++)
        af[i] = *(const v8h*)&sA[(wm + i * 16 + l) * 64 + pa8 * 8];
#pragma unroll
      for (int j = 0; j < 4; j++)
        bfr[j] = *(const v8h*)&sB[(wn + j * 16 + l) * 64 + pa8 * 8];
#pragma unroll
      for (int i = 0; i < 4; i++)
#pragma unroll
        for (int j = 0; j < 4; j++)
          acc[i][j] = __builtin_amdgcn_mfma_f32_16x16x32_f16(af[i], bfr[j],
                                                             acc[i][j], 0, 0, 0);
    }
  }

  if (MODE == 0) {
    u16* ob = outb + (size_t)bz * sOb;
#pragma unroll
    for (int i = 0; i < 4; i++)
#pragma unroll
      for (int j = 0; j < 4; j++)
#pragma unroll
        for (int r = 0; r < 4; r++) {
          int row = m0 + wm + i * 16 + q * 4 + r;
          int col = n0 + wn + j * 16 + l;
          ob[(size_t)row * 256 + col] = f2h(acc[i][j][r]);
        }
  } else {
    u16* Sb = S + (size_t)bz * ((size_t)NNN * NNN);
    u32* Mrb = Mru + bz * 4096;
    u32* Mcb = Mcu + bz * 4096;
#pragma unroll
    for (int i = 0; i < 4; i++)
#pragma unroll
      for (int j = 0; j < 4; j++)
#pragma unroll
        for (int r = 0; r < 4; r++) {
          int row = m0 + wm + i * 16 + q * 4 + r;  // S row n
          int col = n0 + wn + j * 16 + l;          // S col m
          Sb[(size_t)row * NNN + col] = f2h(acc[i][j][r]);
        }
    // --- row max (over this block's 128 cols) ---
    float rm[4][4];
#pragma unroll
    for (int i = 0; i < 4; i++)
#pragma unroll
      for (int r = 0; r < 4; r++)
        rm[i][r] = fmaxf(fmaxf(acc[i][0][r], acc[i][1][r]),
                         fmaxf(acc[i][2][r], acc[i][3][r]));
#pragma unroll
    for (int off = 1; off < 16; off <<= 1)
#pragma unroll
      for (int i = 0; i < 4; i++)
#pragma unroll
        for (int r = 0; r < 4; r++)
          rm[i][r] = fmaxf(rm[i][r], __shfl_xor(rm[i][r], off));
    if (l == 0) {
#pragma unroll
      for (int i = 0; i < 4; i++)
#pragma unroll
        for (int r = 0; r < 4; r++)
          atomicMax(&Mrb[m0 + wm + i * 16 + q * 4 + r], encf(rm[i][r]));
    }
    // --- col max (over this block's 128 rows) ---
    float cm[4];
#pragma unroll
    for (int j = 0; j < 4; j++) {
      float v = -3e38f;
#pragma unroll
      for (int i = 0; i < 4; i++)
#pragma unroll
        for (int r = 0; r < 4; r++) v = fmaxf(v, acc[i][j][r]);
      cm[j] = v;
    }
#pragma unroll
    for (int off = 16; off < 64; off <<= 1)
#pragma unroll
      for (int j = 0; j < 4; j++) cm[j] = fmaxf(cm[j], __shfl_xor(cm[j], off));
    if (q == 0) {
#pragma unroll
      for (int j = 0; j < 4; j++)
        atomicMax(&Mcb[n0 + wn + j * 16 + l], encf(cm[j]));
    }
  }
}

// ---- K-split PV partial, ALL 4 BATCHES in one launch (2048 blocks;
// bp = lin>>9, rest identical to the verified per-batch decode — the
// R5 batch-pair transform extended; rounds {3,3,2} blocks/CU amortize
// the tail that hurt R5's 2-batch version). fp16 V/P/S; partials now
// written fp16 (rel 2^-11 on numerator -> ~2e-3 abs on output). ----
__global__ __launch_bounds__(256) void pv_part(
    const u16* __restrict__ aV, const u16* __restrict__ bV,
    const u16* __restrict__ S, const u32* __restrict__ Mru,
    const u32* __restrict__ Mcu, u16* __restrict__ part,
    float* __restrict__ Lp) {
  const int lin2 = blockIdx.x + 64 * (blockIdx.y + 4 * blockIdx.z);  // 0..2047
  const int bp = lin2 >> 9;   // batch
  const int lin = lin2 & 511; // per-batch block id (baseline decode)
  const int xcd = lin & 7;
  const int which = xcd & 1;
  const int split = xcd >> 1;
  const int x0 = (lin >> 3) * 64;
  const u16* Av = (which ? bV : aV) + (size_t)bp * (CC * NNN);
  const u32* Mst = (which ? Mru : Mcu) + bp * 4096;
  const u16* Sg = S + (size_t)bp * ((size_t)NNN * NNN);
  u16* Out = part + ((size_t)bp * 8 + (size_t)split * 2 + which) * (CC * NNN);
  float* Lpo = Lp + ((size_t)bp * 8 + (size_t)split * 2 + which) * NNN;

  const int tid = threadIdx.x;
  const int wave = tid >> 6, lane = tid & 63, q = lane >> 4, l = lane & 15;
  const int l7 = l & 7;
  const int sr = lane >> 3, sp = lane & 7, sg = sp ^ sr;
  // which=1 S-read coords: 64 x-rows x 4 chunks of 16 k
  const int xl = tid >> 2, ch = tid & 3;
  // which=0 S-read coords: 64 x-cols x 4 groups of 16 k-rows
  const int xs = tid & 63, kq = (tid >> 6) * 16;

  __shared__ alignas(16) u16 sA[256 * 64];
  __shared__ alignas(16) u16 sB[64 * 64];
  __shared__ float lsh[256];

  v4f zero = {0.f, 0.f, 0.f, 0.f};
  v4f acc[4][4];
#pragma unroll
  for (int i = 0; i < 4; i++)
#pragma unroll
    for (int j = 0; j < 4; j++) acc[i][j] = zero;

  const float mx = decf(Mst[x0 + (which ? xl : xs)]);
  float lsum = 0.f;
  const int kbeg = split * 1024;

  for (int k0 = kbeg; k0 < kbeg + 1024; k0 += 64) {
    __syncthreads();
#pragma unroll
    for (int ii = 0; ii < 8; ii++) {
      int r = wave * 64 + ii * 8 + sr;
      async16(Av + (size_t)r * NNN + k0 + sg * 8, &sA[r * 64 + sp * 8]);
    }
    if (which) {
      const u16* gp = Sg + (size_t)(x0 + xl) * NNN + k0 + ch * 16;
      v8h h0 = *(const v8h*)gp;
      v8h h1 = *(const v8h*)(gp + 8);
      float e[16];
#pragma unroll
      for (int t = 0; t < 8; t++) {
        e[t] = __expf((float)h0[t] - mx);
        e[t + 8] = __expf((float)h1[t] - mx);
      }
#pragma unroll
      for (int t = 0; t < 16; t++) lsum += e[t];
      v8h pk0, pk1;
#pragma unroll
      for (int t = 0; t < 8; t++) {
        pk0[t] = (f16)e[t];
        pk1[t] = (f16)e[t + 8];
      }
      const int g0 = ch * 2;
      *(v8h*)&sB[xl * 64 + (g0 ^ (xl & 7)) * 8] = pk0;
      *(v8h*)&sB[xl * 64 + ((g0 + 1) ^ (xl & 7)) * 8] = pk1;
    } else {
      const u16* gp = Sg + (size_t)(k0 + kq) * NNN + x0 + xs;
      float e[16];
#pragma unroll
      for (int t = 0; t < 16; t++)
        e[t] = __expf((float)(*(const f16*)&gp[(size_t)t * NNN]) - mx);
#pragma unroll
      for (int t = 0; t < 16; t++) lsum += e[t];
      v8h pk0, pk1;
#pragma unroll
      for (int t = 0; t < 8; t++) {
        pk0[t] = (f16)e[t];
        pk1[t] = (f16)e[t + 8];
      }
      const int g0 = (tid >> 6) * 2;
      *(v8h*)&sB[xs * 64 + (g0 ^ (xs & 7)) * 8] = pk0;
      *(v8h*)&sB[xs * 64 + ((g0 + 1) ^ (xs & 7)) * 8] = pk1;
    }
    __syncthreads();
#pragma unroll
    for (int s = 0; s < 2; s++) {
      const int pa8 = (s * 4 + q) ^ l7;
      v8h af[4], bfr[4];
#pragma unroll
      for (int i = 0; i < 4; i++)
        af[i] = *(const v8h*)&sA[(wave * 64 + i * 16 + l) * 64 + pa8 * 8];
#pragma unroll
      for (int j = 0; j < 4; j++)
        bfr[j] = *(const v8h*)&sB[(j * 16 + l) * 64 + pa8 * 8];
#pragma unroll
      for (int i = 0; i < 4; i++)
#pragma unroll
        for (int j = 0; j < 4; j++)
          acc[i][j] = __builtin_amdgcn_mfma_f32_16x16x32_f16(af[i], bfr[j],
                                                             acc[i][j], 0, 0, 0);
    }
  }

  // L partial reduction: 4 threads contribute per x
  __syncthreads();
  lsh[tid] = lsum;
  __syncthreads();
  if (tid < 64) {
    float t;
    if (which)
      t = (lsh[tid * 4] + lsh[tid * 4 + 1]) + (lsh[tid * 4 + 2] + lsh[tid * 4 + 3]);
    else
      t = (lsh[tid] + lsh[tid + 64]) + (lsh[tid + 128] + lsh[tid + 192]);
    Lpo[x0 + tid] = t;
  }

#pragma unroll
  for (int i = 0; i < 4; i++)
#pragma unroll
    for (int j = 0; j < 4; j++)
#pragma unroll
      for (int r = 0; r < 4; r++) {
        int c = wave * 64 + i * 16 + q * 4 + r;
        int x = x0 + j * 16 + l;
        Out[(size_t)c * NNN + x] = f2h(acc[i][j][r]);
      }
}

// ---- reduce 4 K-split fp16 partials + L partials, apply 1/L, write out.
// All 4 batches in one launch: 2048 blocks, bp = bi>>9. ----
__global__ __launch_bounds__(256) void pv_reduce(
    const u16* __restrict__ part, const float* __restrict__ Lp,
    float* __restrict__ outA, float* __restrict__ outB) {
  const int bi = blockIdx.x;  // 0..2047
  const int bp = bi >> 9;
  const int which = (bi >> 8) & 1;
  const int c = bi & 255;
  float* Out = (which ? outB : outA) + (size_t)bp * CC * NNN +
               (size_t)c * NNN;
  const u16* p0 = part + (size_t)bp * 8 * (CC * NNN) +
                  (size_t)which * (CC * NNN) + (size_t)c * NNN;
  const float* l0 = Lp + (size_t)bp * 8 * NNN + (size_t)which * NNN;
  const size_t ps = 2 * (size_t)CC * NNN;
  const size_t ls = 2 * (size_t)NNN;
  const int t = threadIdx.x;
#pragma unroll
  for (int xi = 0; xi < 4; xi++) {
    int x = xi * 1024 + t * 4;
    float sx = 0.f, sy = 0.f, sz = 0.f, sw = 0.f;
    float lx = 0.f, ly = 0.f, lz = 0.f, lw = 0.f;
#pragma unroll
    for (int u = 0; u < 4; u++) {
      ushort4 h = *(const ushort4*)(p0 + (size_t)u * ps + x);
      float4 lv = *(const float4*)(l0 + (size_t)u * ls + x);
      sx += h2f(h.x); sy += h2f(h.y); sz += h2f(h.z); sw += h2f(h.w);
      lx += lv.x; ly += lv.y; lz += lv.z; lw += lv.w;
    }
    float4 o;
    o.x = sx / lx;
    o.y = sy / ly;
    o.z = sz / lz;
    o.w = sw / lw;
    *(float4*)(Out + x) = o;
  }
}

extern "C" void kernel_launch(void* const* d_in, const int* in_sizes, int n_in,
                              void* d_out, int out_size, void* d_ws,
                              size_t ws_size, hipStream_t stream) {
  const float* a = (const float*)d_in[0];
  const float* b = (const float*)d_in[1];
  const float* W = (const float*)d_in[2];
  float* out = (float*)d_out;

  char* ws = (char*)d_ws;
  u16* Ws = (u16*)(ws);                     // 131072 (256KB rsvd)
  u16* aT = (u16*)(ws + 262144);            // 8388608
  u16* bT = (u16*)(ws + 8650752);           // 8388608
  u16* aCb = (u16*)(ws + 17039360);         // 8388608
  u16* bCb = (u16*)(ws + 25427968);         // 8388608
  u16* ats = (u16*)(ws + 33816576);         // 8388608 (16MB rsvd)
  u32* Mru = (u32*)(ws + 50593792);         // [4][4096] u32 = 65536
  u32* Mcu = (u32*)(ws + 50659328);         // 65536
  float* Lp = (float*)(ws + 50724864);      // 4*8*4096*4 = 524288
  u16* Sbuf = (u16*)(ws + 51249152);        // 4 batches fp16 = 134217728
  u16* Ppart = (u16*)(ws + 185466880);      // 4*8 slabs fp16 = 67108864
                                            // ends 252575744 < 256 MiB ws

  wsplit<<<dim3(256), 256, 0, stream>>>(W, Ws);
  tsplit<<<dim3(64, 4, 8), 256, 0, stream>>>(a, b, aT, bT, aCb, bCb);
  // a~[n][d] = sum_c aT[n][c] * W[d][c], K=256, out single fp16 pitch 256
  gemm_tn<0><<<dim3(32, 2, 4), 256, 0, stream>>>(
      aT, (long)NNN * 256, 256, 255, Ws, 0, 256, 255, 256,
      ats, (long)NNN * 256, nullptr, nullptr, nullptr);
  hipMemsetAsync(Mru, 0, 131072, stream);  // all 4 batches' Mru+Mcu

  // S[n][m] for all 4 batches in one launch (z = batch)
  gemm_tn<1><<<dim3(32, 32, 4), 256, 0, stream>>>(
      ats, (long)NNN * 256, 256, 255, bT, (long)NNN * 256, 256, 255, 256,
      nullptr, 0, Sbuf, Mru, Mcu);
  pv_part<<<dim3(64, 4, 8), 256, 0, stream>>>(
      aCb, bCb, Sbuf, Mru, Mcu, Ppart, Lp);
  pv_reduce<<<dim3(2048), 256, 0, stream>>>(
      Ppart, Lp, out, out + 4194304);
}

// Round 13
// 292.467 us; speedup vs baseline: 1.9508x; 1.1010x over previous
//
#include <hip/hip_runtime.h>
#include <stdint.h>

typedef unsigned short u16;
typedef unsigned int u32;
typedef _Float16 f16;
typedef float v4f __attribute__((ext_vector_type(4)));
typedef f16 v8h __attribute__((ext_vector_type(8)));

#define CC 256
#define NNN 4096

__device__ __forceinline__ u16 f2h(float f) {
  union { f16 h; u16 u; } c; c.h = (f16)f; return c.u;
}
__device__ __forceinline__ float h2f(u16 u) {
  union { f16 h; u16 u; } c; c.u = u; return (float)c.h;
}
// monotone float<->uint encoding for atomicMax on fp32
__device__ __forceinline__ u32 encf(float f) {
  u32 u = __float_as_uint(f);
  return (u >> 31) ? ~u : (u | 0x80000000u);
}
__device__ __forceinline__ float decf(u32 u) {
  return (u >> 31) ? __uint_as_float(u & 0x7fffffffu) : __uint_as_float(~u);
}
__device__ __forceinline__ void async16(const void* g, void* l) {
  __builtin_amdgcn_global_load_lds(
      (const __attribute__((address_space(1))) uint32_t*)g,
      (__attribute__((address_space(3))) uint32_t*)l, 16, 0, 0);
}

// ---- W [256][256] fp32 -> Ws [256][256] single fp16, K(c)-fast ----
__global__ __launch_bounds__(256) void wsplit(const float* __restrict__ W,
                                              u16* __restrict__ Ws) {
  const int d = blockIdx.x, c = threadIdx.x;
  Ws[d * 256 + c] = f2h(W[d * 256 + c]);
}

// ---- both inputs, all batches: in [C][N] fp32 -> T [N][256] fp16
// (transposed) and Cb [C][N] fp16 copy. z = batch(0..3) | which<<2. ----
__global__ __launch_bounds__(256) void tsplit(
    const float* __restrict__ asrc, const float* __restrict__ bsrc,
    u16* __restrict__ aT, u16* __restrict__ bT,
    u16* __restrict__ aCb, u16* __restrict__ bCb) {
  __shared__ u16 th[64][65];
  const int bz = blockIdx.z;
  const int bb = bz & 3;
  const int wh = bz >> 2;
  const int n0 = blockIdx.x * 64;
  const int c0 = blockIdx.y * 64;
  const int tx = threadIdx.x & 63;
  const int ty = threadIdx.x >> 6;  // 0..3
  const float* ib = (wh ? bsrc : asrc) + (size_t)bb * CC * NNN;
  u16* Tb = (wh ? bT : aT) + (size_t)bb * NNN * 256;
  u16* Cbb = (wh ? bCb : aCb) + (size_t)bb * CC * NNN;
#pragma unroll
  for (int k = 0; k < 16; k++) {
    int r = ty + k * 4;
    float v = ib[(size_t)(c0 + r) * NNN + n0 + tx];
    u16 h = f2h(v);
    th[r][tx] = h;
    Cbb[(size_t)(c0 + r) * NNN + n0 + tx] = h;
  }
  __syncthreads();
#pragma unroll
  for (int k = 0; k < 16; k++) {
    int r = ty + k * 4;
    Tb[(size_t)(n0 + r) * 256 + c0 + tx] = th[tx][r];
  }
}

// ---- TN GEMM over fp16, K=256. BK=64, XOR-swizzled LDS.
// MODE 0: out = a~ single fp16, pitch 256.
// MODE 1: out = S fp16 + row/col max atomics; per-z batch slabs;
//         tiles XCD-clustered in xy.
template <int MODE>
__global__ __launch_bounds__(256) void gemm_tn(
    const u16* __restrict__ A, long sAb, int pa, int ma,
    const u16* __restrict__ Bm, long sBb, int pb, int mb, int ktot,
    u16* __restrict__ outb, long sOb, u16* __restrict__ S,
    u32* __restrict__ Mru, u32* __restrict__ Mcu) {
  const int bz = blockIdx.z;
  const u16* Ab = A + (size_t)bz * sAb;
  const u16* Bb = Bm + (size_t)bz * sBb;
  int m0, n0;
  if (MODE == 0) {
    m0 = blockIdx.x * 128;
    n0 = blockIdx.y * 128;
  } else {
    const int bidl = blockIdx.x + (int)gridDim.x * blockIdx.y;  // 0..1023
    const int xcd = bidl & 7, idx = bidl >> 3;
    const int mt = (xcd & 3) * 8 + (idx & 7);
    const int nt = (xcd >> 2) * 16 + (idx >> 3);
    m0 = mt * 128;
    n0 = nt * 128;
  }
  const int tid = threadIdx.x;
  const int wave = tid >> 6;
  const int lane = tid & 63;
  const int q = lane >> 4;
  const int l = lane & 15;
  const int l7 = l & 7;
  const int wm = (wave >> 1) * 64;
  const int wn = (wave & 1) * 64;
  const int sr = lane >> 3;  // row-in-group 0..7
  const int sp = lane & 7;   // LDS chunk position 0..7
  const int sg = sp ^ sr;    // global chunk index (swizzle)

  __shared__ alignas(16) u16 sA[128 * 64];
  __shared__ alignas(16) u16 sB[128 * 64];

  v4f zero = {0.f, 0.f, 0.f, 0.f};
  v4f acc[4][4];
#pragma unroll
  for (int i = 0; i < 4; i++)
#pragma unroll
    for (int j = 0; j < 4; j++) acc[i][j] = zero;

  for (int k0 = 0; k0 < ktot; k0 += 64) {
    const int kA = k0 & ma;
    const int kB = k0 & mb;
    __syncthreads();
#pragma unroll
    for (int ii = 0; ii < 4; ii++) {
      int r = wave * 32 + ii * 8 + sr;
      async16(Ab + (size_t)(m0 + r) * pa + kA + sg * 8,
              &sA[r * 64 + sp * 8]);
    }
#pragma unroll
    for (int ii = 0; ii < 4; ii++) {
      int r = wave * 32 + ii * 8 + sr;
      async16(Bb + (size_t)(n0 + r) * pb + kB + sg * 8,
              &sB[r * 64 + sp * 8]);
    }
    __syncthreads();
#pragma unroll
    for (int s = 0; s < 2; s++) {
      const int pa8 = (s * 4 + q) ^ l7;
      v8h af[4], bfr[4];
#pragma unroll
      for (int i = 0; i < 4; i++)
        af[i] = *(const v8h*)&sA[(wm + i * 16 + l) * 64 + pa8 * 8];
#pragma unroll
      for (int j = 0; j < 4; j++)
        bfr[j] = *(const v8h*)&sB[(wn + j * 16 + l) * 64 + pa8 * 8];
#pragma unroll
      for (int i = 0; i < 4; i++)
#pragma unroll
        for (int j = 0; j < 4; j++)
          acc[i][j] = __builtin_amdgcn_mfma_f32_16x16x32_f16(af[i], bfr[j],
                                                             acc[i][j], 0, 0, 0);
    }
  }

  if (MODE == 0) {
    u16* ob = outb + (size_t)bz * sOb;
#pragma unroll
    for (int i = 0; i < 4; i++)
#pragma unroll
      for (int j = 0; j < 4; j++)
#pragma unroll
        for (int r = 0; r < 4; r++) {
          int row = m0 + wm + i * 16 + q * 4 + r;
          int col = n0 + wn + j * 16 + l;
          ob[(size_t)row * 256 + col] = f2h(acc[i][j][r]);
        }
  } else {
    u16* Sb = S + (size_t)bz * ((size_t)NNN * NNN);
    u32* Mrb = Mru + bz * 4096;
    u32* Mcb = Mcu + bz * 4096;
#pragma unroll
    for (int i = 0; i < 4; i++)
#pragma unroll
      for (int j = 0; j < 4; j++)
#pragma unroll
        for (int r = 0; r < 4; r++) {
          int row = m0 + wm + i * 16 + q * 4 + r;  // S row n
          int col = n0 + wn + j * 16 + l;          // S col m
          Sb[(size_t)row * NNN + col] = f2h(acc[i][j][r]);
        }
    // --- row max (over this block's 128 cols) ---
    float rm[4][4];
#pragma unroll
    for (int i = 0; i < 4; i++)
#pragma unroll
      for (int r = 0; r < 4; r++)
        rm[i][r] = fmaxf(fmaxf(acc[i][0][r], acc[i][1][r]),
                         fmaxf(acc[i][2][r], acc[i][3][r]));
#pragma unroll
    for (int off = 1; off < 16; off <<= 1)
#pragma unroll
      for (int i = 0; i < 4; i++)
#pragma unroll
        for (int r = 0; r < 4; r++)
          rm[i][r] = fmaxf(rm[i][r], __shfl_xor(rm[i][r], off));
    if (l == 0) {
#pragma unroll
      for (int i = 0; i < 4; i++)
#pragma unroll
        for (int r = 0; r < 4; r++)
          atomicMax(&Mrb[m0 + wm + i * 16 + q * 4 + r], encf(rm[i][r]));
    }
    // --- col max (over this block's 128 rows) ---
    float cm[4];
#pragma unroll
    for (int j = 0; j < 4; j++) {
      float v = -3e38f;
#pragma unroll
      for (int i = 0; i < 4; i++)
#pragma unroll
        for (int r = 0; r < 4; r++) v = fmaxf(v, acc[i][j][r]);
      cm[j] = v;
    }
#pragma unroll
    for (int off = 16; off < 64; off <<= 1)
#pragma unroll
      for (int j = 0; j < 4; j++) cm[j] = fmaxf(cm[j], __shfl_xor(cm[j], off));
    if (q == 0) {
#pragma unroll
      for (int j = 0; j < 4; j++)
        atomicMax(&Mcb[n0 + wn + j * 16 + l], encf(cm[j]));
    }
  }
}

// ---- FULL-K PV, all 4 batches, no k-split, fused divide.
// 512 blocks = 4 batches x 2 sides x 64 x-tiles = exactly 2 blocks/CU,
// zero tail rounds; total step-slots/CU identical to the R12 split-4
// version (2048x16 == 512x64). Each XCD owns one (batch,which) combo:
// its 2 MB V slab is L2-resident, its 32 MB S slab streams once.
// Inner loop byte-identical to R12; L complete at loop end -> multiply
// by 1/L and write fp32 out directly (Ppart + pv_reduce deleted).
__global__ __launch_bounds__(256) void pv_part(
    const u16* __restrict__ aV, const u16* __restrict__ bV,
    const u16* __restrict__ S, const u32* __restrict__ Mru,
    const u32* __restrict__ Mcu, float* __restrict__ outA,
    float* __restrict__ outB) {
  const int lin = blockIdx.x + 64 * (blockIdx.y + 2 * blockIdx.z);  // 0..511
  const int xcd = lin & 7;
  const int which = xcd & 1;
  const int bp = xcd >> 1;         // batch 0..3
  const int x0 = (lin >> 3) * 64;  // 64 x-tiles
  const u16* Av = (which ? bV : aV) + (size_t)bp * (CC * NNN);
  const u32* Mst = (which ? Mru : Mcu) + bp * 4096;
  const u16* Sg = S + (size_t)bp * ((size_t)NNN * NNN);
  float* Outp = (which ? outB : outA) + (size_t)bp * CC * NNN;

  const int tid = threadIdx.x;
  const int wave = tid >> 6, lane = tid & 63, q = lane >> 4, l = lane & 15;
  const int l7 = l & 7;
  const int sr = lane >> 3, sp = lane & 7, sg = sp ^ sr;
  // which=1 S-read coords: 64 x-rows x 4 chunks of 16 k
  const int xl = tid >> 2, ch = tid & 3;
  // which=0 S-read coords: 64 x-cols x 4 groups of 16 k-rows
  const int xs = tid & 63, kq = (tid >> 6) * 16;

  __shared__ alignas(16) u16 sA[256 * 64];
  __shared__ alignas(16) u16 sB[64 * 64];
  __shared__ float lsh[256];
  __shared__ float Lx[64];

  v4f zero = {0.f, 0.f, 0.f, 0.f};
  v4f acc[4][4];
#pragma unroll
  for (int i = 0; i < 4; i++)
#pragma unroll
    for (int j = 0; j < 4; j++) acc[i][j] = zero;

  const float mx = decf(Mst[x0 + (which ? xl : xs)]);
  float lsum = 0.f;

  for (int k0 = 0; k0 < NNN; k0 += 64) {
    __syncthreads();
#pragma unroll
    for (int ii = 0; ii < 8; ii++) {
      int r = wave * 64 + ii * 8 + sr;
      async16(Av + (size_t)r * NNN + k0 + sg * 8, &sA[r * 64 + sp * 8]);
    }
    if (which) {
      const u16* gp = Sg + (size_t)(x0 + xl) * NNN + k0 + ch * 16;
      v8h h0 = *(const v8h*)gp;
      v8h h1 = *(const v8h*)(gp + 8);
      float e[16];
#pragma unroll
      for (int t = 0; t < 8; t++) {
        e[t] = __expf((float)h0[t] - mx);
        e[t + 8] = __expf((float)h1[t] - mx);
      }
#pragma unroll
      for (int t = 0; t < 16; t++) lsum += e[t];
      v8h pk0, pk1;
#pragma unroll
      for (int t = 0; t < 8; t++) {
        pk0[t] = (f16)e[t];
        pk1[t] = (f16)e[t + 8];
      }
      const int g0 = ch * 2;
      *(v8h*)&sB[xl * 64 + (g0 ^ (xl & 7)) * 8] = pk0;
      *(v8h*)&sB[xl * 64 + ((g0 + 1) ^ (xl & 7)) * 8] = pk1;
    } else {
      const u16* gp = Sg + (size_t)(k0 + kq) * NNN + x0 + xs;
      float e[16];
#pragma unroll
      for (int t = 0; t < 16; t++)
        e[t] = __expf((float)(*(const f16*)&gp[(size_t)t * NNN]) - mx);
#pragma unroll
      for (int t = 0; t < 16; t++) lsum += e[t];
      v8h pk0, pk1;
#pragma unroll
      for (int t = 0; t < 8; t++) {
        pk0[t] = (f16)e[t];
        pk1[t] = (f16)e[t + 8];
      }
      const int g0 = (tid >> 6) * 2;
      *(v8h*)&sB[xs * 64 + (g0 ^ (xs & 7)) * 8] = pk0;
      *(v8h*)&sB[xs * 64 + ((g0 + 1) ^ (xs & 7)) * 8] = pk1;
    }
    __syncthreads();
#pragma unroll
    for (int s = 0; s < 2; s++) {
      const int pa8 = (s * 4 + q) ^ l7;
      v8h af[4], bfr[4];
#pragma unroll
      for (int i = 0; i < 4; i++)
        af[i] = *(const v8h*)&sA[(wave * 64 + i * 16 + l) * 64 + pa8 * 8];
#pragma unroll
      for (int j = 0; j < 4; j++)
        bfr[j] = *(const v8h*)&sB[(j * 16 + l) * 64 + pa8 * 8];
#pragma unroll
      for (int i = 0; i < 4; i++)
#pragma unroll
        for (int j = 0; j < 4; j++)
          acc[i][j] = __builtin_amdgcn_mfma_f32_16x16x32_f16(af[i], bfr[j],
                                                             acc[i][j], 0, 0, 0);
    }
  }

  // L reduction: 4 threads contribute per x -> Lx = 1/L
  __syncthreads();
  lsh[tid] = lsum;
  __syncthreads();
  if (tid < 64) {
    float t;
    if (which)
      t = (lsh[tid * 4] + lsh[tid * 4 + 1]) + (lsh[tid * 4 + 2] + lsh[tid * 4 + 3]);
    else
      t = (lsh[tid] + lsh[tid + 64]) + (lsh[tid + 128] + lsh[tid + 192]);
    Lx[tid] = 1.0f / t;
  }
  __syncthreads();

#pragma unroll
  for (int i = 0; i < 4; i++)
#pragma unroll
    for (int j = 0; j < 4; j++) {
      const float rl = Lx[j * 16 + l];
#pragma unroll
      for (int r = 0; r < 4; r++) {
        int c = wave * 64 + i * 16 + q * 4 + r;
        Outp[(size_t)c * NNN + x0 + j * 16 + l] = acc[i][j][r] * rl;
      }
    }
}

extern "C" void kernel_launch(void* const* d_in, const int* in_sizes, int n_in,
                              void* d_out, int out_size, void* d_ws,
                              size_t ws_size, hipStream_t stream) {
  const float* a = (const float*)d_in[0];
  const float* b = (const float*)d_in[1];
  const float* W = (const float*)d_in[2];
  float* out = (float*)d_out;

  char* ws = (char*)d_ws;
  u16* Ws = (u16*)(ws);                     // 131072 (256KB rsvd)
  u16* aT = (u16*)(ws + 262144);            // 8388608
  u16* bT = (u16*)(ws + 8650752);           // 8388608
  u16* aCb = (u16*)(ws + 17039360);         // 8388608
  u16* bCb = (u16*)(ws + 25427968);         // 8388608
  u16* ats = (u16*)(ws + 33816576);         // 8388608 (16MB rsvd)
  u32* Mru = (u32*)(ws + 50593792);         // [4][4096] u32 = 65536
  u32* Mcu = (u32*)(ws + 50659328);         // 65536
  u16* Sbuf = (u16*)(ws + 51249152);        // 4 batches fp16 = 134217728
                                            // ends ~185.5 MB

  wsplit<<<dim3(256), 256, 0, stream>>>(W, Ws);
  tsplit<<<dim3(64, 4, 8), 256, 0, stream>>>(a, b, aT, bT, aCb, bCb);
  // a~[n][d] = sum_c aT[n][c] * W[d][c], K=256, out single fp16 pitch 256
  gemm_tn<0><<<dim3(32, 2, 4), 256, 0, stream>>>(
      aT, (long)NNN * 256, 256, 255, Ws, 0, 256, 255, 256,
      ats, (long)NNN * 256, nullptr, nullptr, nullptr);
  hipMemsetAsync(Mru, 0, 131072, stream);  // all 4 batches' Mru+Mcu

  // S[n][m] for all 4 batches in one launch (z = batch)
  gemm_tn<1><<<dim3(32, 32, 4), 256, 0, stream>>>(
      ats, (long)NNN * 256, 256, 255, bT, (long)NNN * 256, 256, 255, 256,
      nullptr, 0, Sbuf, Mru, Mcu);
  // full-K PV + softmax-divide, writes out directly
  pv_part<<<dim3(64, 2, 4), 256, 0, stream>>>(
      aCb, bCb, Sbuf, Mru, Mcu, out, out + 4194304);
}